// Round 2
// baseline (345.191 us; speedup 1.0000x reference)
//
#include <hip/hip_runtime.h>

typedef unsigned short u16;
typedef u16 u16x4 __attribute__((ext_vector_type(4)));
typedef float f32x4 __attribute__((ext_vector_type(4)));
typedef __bf16 bf16x8 __attribute__((ext_vector_type(8)));

#define M_DIM 8192   // B*H = 4*2048
#define N_DIM 1024   // O
#define K_DIM 4096   // I*(D+1) = 1024*4
#define K_SPLIT 2
#define K_PER (K_DIM / K_SPLIT)  // 2048

__device__ __forceinline__ u16 f2bf(float f) {
  unsigned u = __float_as_uint(f);
  u += 0x7FFFu + ((u >> 16) & 1u);   // round-to-nearest-even
  return (u16)(u >> 16);
}

// ---- kernel 1: x fp32 -> bf16. 4 elems/thread so every instruction is
// lane-contiguous: 16B/lane read (1KB/wave), 8B/lane write (512B/wave). ----
__global__ __launch_bounds__(256) void k_cvt(const float* __restrict__ x,
                                             u16* __restrict__ y) {
  long i = ((long)blockIdx.x * 256 + threadIdx.x) * 4;
  f32x4 a = *(const f32x4*)(x + i);
  u16x4 r;
  r[0] = f2bf(a[0]); r[1] = f2bf(a[1]); r[2] = f2bf(a[2]); r[3] = f2bf(a[3]);
  *(u16x4*)(y + i) = r;
}

// ---- kernel 2: W2[o][i*4+d] = ws[o][i] * w[o][d], bf16 [N][K] ----
__global__ __launch_bounds__(256) void k_w2(const float* __restrict__ w,
                                            const float* __restrict__ ws,
                                            u16* __restrict__ w2) {
  int idx = blockIdx.x * 256 + threadIdx.x;  // idx = o*1024 + i
  int o = idx >> 10;
  float s = ws[idx];
  f32x4 wv = *(const f32x4*)(w + o * 4);
  u16x4 r;
  r[0] = f2bf(s * wv[0]); r[1] = f2bf(s * wv[1]);
  r[2] = f2bf(s * wv[2]); r[3] = f2bf(s * wv[3]);
  *(u16x4*)(w2 + (size_t)idx * 4) = r;
}

// ---- kernel 3: m97-style bf16 GEMM with split-K=2.
// C[M][N] += A[M][K] @ Bt[N][K]^T, each z-block does half of K, atomicAdd
// epilogue (d_out pre-zeroed by hipMemsetAsync). ----
typedef __attribute__((address_space(1))) const void gvoid_t;
typedef __attribute__((address_space(3))) void lvoid_t;
__device__ __forceinline__ void gll16(const void* g, void* l) {
  __builtin_amdgcn_global_load_lds((gvoid_t*)g, (lvoid_t*)l, 16, 0, 0);
}

__global__ __launch_bounds__(256) void k_gemm(const u16* __restrict__ A,
                                              const u16* __restrict__ Bt,
                                              float* __restrict__ C) {
  __shared__ u16 sA[128 * 32];  // 8 KB, unpadded: global_load_lds lane-contiguous
  __shared__ u16 sB[128 * 32];  // 8 KB

  const int t    = threadIdx.x;
  const int lane = t & 63;
  const int wid  = t >> 6;
  const int m0   = blockIdx.y * 128;
  const int n0   = blockIdx.x * 128;
  const int kb   = blockIdx.z * K_PER;

  // staging: chunk c = t (+256 for 2nd round); row = c>>2, k-off = (c&3)*8
  const int row0 = t >> 2;
  const int kc0  = (t & 3) * 8;
  const u16* gA0 = A  + (size_t)(m0 + row0) * K_DIM + kb + kc0;
  const u16* gA1 = gA0 + (size_t)64 * K_DIM;
  const u16* gB0 = Bt + (size_t)(n0 + row0) * K_DIM + kb + kc0;
  const u16* gB1 = gB0 + (size_t)64 * K_DIM;
  u16* lA0 = sA + t * 8;
  u16* lA1 = sA + (t + 256) * 8;
  u16* lB0 = sB + t * 8;
  u16* lB1 = sB + (t + 256) * 8;

  // wave tile: 2x2 waves of 64x64, each 4x4 MFMA 16x16
  const int wm = (wid >> 1) * 64;
  const int wn = (wid & 1) * 64;
  const int fr = lane & 15;         // A/B fragment row: m (or n) = lane&15
  const int kg = (lane >> 4) * 8;   // k = (lane>>4)*8 + j

  f32x4 acc[4][4];
#pragma unroll
  for (int i = 0; i < 4; i++)
#pragma unroll
    for (int j = 0; j < 4; j++) acc[i][j] = (f32x4){0.f, 0.f, 0.f, 0.f};

  for (int k0 = 0; k0 < K_PER; k0 += 32) {
    gll16(gA0, lA0); gll16(gA1, lA1);
    gll16(gB0, lB0); gll16(gB1, lB1);
    gA0 += 32; gA1 += 32; gB0 += 32; gB1 += 32;
    __syncthreads();  // barrier drains vmcnt -> LDS tiles ready

    bf16x8 af[4], bf[4];
#pragma unroll
    for (int mi = 0; mi < 4; mi++)
      af[mi] = *(const bf16x8*)(sA + (wm + mi * 16 + fr) * 32 + kg);
#pragma unroll
    for (int ni = 0; ni < 4; ni++)
      bf[ni] = *(const bf16x8*)(sB + (wn + ni * 16 + fr) * 32 + kg);

#pragma unroll
    for (int mi = 0; mi < 4; mi++)
#pragma unroll
      for (int ni = 0; ni < 4; ni++)
        acc[mi][ni] = __builtin_amdgcn_mfma_f32_16x16x32_bf16(
            af[mi], bf[ni], acc[mi][ni], 0, 0, 0);
    __syncthreads();  // protect LDS from next iteration's staging
  }

  // C/D layout: col = lane&15, row = (lane>>4)*4 + reg
  const int cr = (lane >> 4) * 4;
  const int cc = lane & 15;
#pragma unroll
  for (int mi = 0; mi < 4; mi++)
#pragma unroll
    for (int ni = 0; ni < 4; ni++) {
      float* cp = C + (size_t)(m0 + wm + mi * 16 + cr) * N_DIM +
                  (n0 + wn + ni * 16 + cc);
#pragma unroll
      for (int r = 0; r < 4; r++)
        atomicAdd(cp + (size_t)r * N_DIM, acc[mi][ni][r]);
    }
}

extern "C" void kernel_launch(void* const* d_in, const int* in_sizes, int n_in,
                              void* d_out, int out_size, void* d_ws, size_t ws_size,
                              hipStream_t stream) {
  const float* x  = (const float*)d_in[0];   // (4,2048,1024,4) fp32
  const float* w  = (const float*)d_in[1];   // (1024,4) fp32
  const float* ws = (const float*)d_in[2];   // (1024,1024) fp32
  float* out = (float*)d_out;                // (4,2048,1024) fp32 = C[M][N]

  u16* xbf = (u16*)d_ws;                         // 33.5M u16 = 64 MB
  u16* w2  = xbf + (size_t)M_DIM * K_DIM;        // 4.2M u16 = 8 MB

  // zero C for the split-K atomic epilogue (graph-capturable stream op)
  hipMemsetAsync(out, 0, (size_t)out_size * sizeof(float), stream);

  // 33,554,432 / (256*4) = 32768 blocks
  k_cvt<<<32768, 256, 0, stream>>>(x, xbf);
  // 1,048,576 / 256 = 4096 blocks
  k_w2<<<4096, 256, 0, stream>>>(w, ws, w2);

  dim3 grid(N_DIM / 128, M_DIM / 128, K_SPLIT);  // (8, 64, 2) = 1024 blocks
  k_gemm<<<grid, 256, 0, stream>>>(xbf, w2, out);
}

// Round 3
// 313.582 us; speedup vs baseline: 1.1008x; 1.1008x over previous
//
#include <hip/hip_runtime.h>

typedef unsigned short u16;
typedef u16 u16x4 __attribute__((ext_vector_type(4)));
typedef float f32x4 __attribute__((ext_vector_type(4)));
typedef __bf16 bf16x8 __attribute__((ext_vector_type(8)));

#define M_DIM 8192   // B*H = 4*2048
#define N_DIM 1024   // O
#define K_DIM 4096   // I*(D+1) = 1024*4

__device__ __forceinline__ u16 f2bf(float f) {
  unsigned u = __float_as_uint(f);
  u += 0x7FFFu + ((u >> 16) & 1u);   // round-to-nearest-even
  return (u16)(u >> 16);
}

// ---- kernel 1: x fp32 -> bf16. 4 elems/thread: every instruction is
// lane-contiguous (16B/lane read, 8B/lane write). ----
__global__ __launch_bounds__(256) void k_cvt(const float* __restrict__ x,
                                             u16* __restrict__ y) {
  long i = ((long)blockIdx.x * 256 + threadIdx.x) * 4;
  f32x4 a = *(const f32x4*)(x + i);
  u16x4 r;
  r[0] = f2bf(a[0]); r[1] = f2bf(a[1]); r[2] = f2bf(a[2]); r[3] = f2bf(a[3]);
  *(u16x4*)(y + i) = r;
}

// ---- kernel 2: W2[o][i*4+d] = ws[o][i] * w[o][d], bf16 [N][K] ----
__global__ __launch_bounds__(256) void k_w2(const float* __restrict__ w,
                                            const float* __restrict__ ws,
                                            u16* __restrict__ w2) {
  int idx = blockIdx.x * 256 + threadIdx.x;  // idx = o*1024 + i
  int o = idx >> 10;
  float s = ws[idx];
  f32x4 wv = *(const f32x4*)(w + o * 4);
  u16x4 r;
  r[0] = f2bf(s * wv[0]); r[1] = f2bf(s * wv[1]);
  r[2] = f2bf(s * wv[2]); r[3] = f2bf(s * wv[3]);
  *(u16x4*)(w2 + (size_t)idx * 4) = r;
}

// ---- kernel 3: bf16 GEMM, 64(M)x128(N) tile -> 1024 blocks = 4/CU.
// C[M][N] = A[M][K] @ Bt[N][K]^T. A re-read 8x (L3, 64MB); B re-read 128x
// but W2 is 8MB, L2-resident, so the extra staging is cheap. ----
typedef __attribute__((address_space(1))) const void gvoid_t;
typedef __attribute__((address_space(3))) void lvoid_t;
__device__ __forceinline__ void gll16(const void* g, void* l) {
  __builtin_amdgcn_global_load_lds((gvoid_t*)g, (lvoid_t*)l, 16, 0, 0);
}

__global__ __launch_bounds__(256) void k_gemm(const u16* __restrict__ A,
                                              const u16* __restrict__ Bt,
                                              float* __restrict__ C) {
  __shared__ u16 sA[64 * 32];   // 4 KB, unpadded (global_load_lds lane-contig)
  __shared__ u16 sB[128 * 32];  // 8 KB

  const int t    = threadIdx.x;
  const int lane = t & 63;
  const int wid  = t >> 6;
  const int m0   = blockIdx.y * 64;
  const int n0   = blockIdx.x * 128;

  // staging: chunk c -> row = c>>2, k-off = (c&3)*8; A needs 1 round (64 rows),
  // B needs 2 rounds (128 rows)
  const int row0 = t >> 2;
  const int kc0  = (t & 3) * 8;
  const u16* gA0 = A  + (size_t)(m0 + row0) * K_DIM + kc0;
  const u16* gB0 = Bt + (size_t)(n0 + row0) * K_DIM + kc0;
  const u16* gB1 = gB0 + (size_t)64 * K_DIM;
  u16* lA0 = sA + t * 8;
  u16* lB0 = sB + t * 8;
  u16* lB1 = sB + (t + 256) * 8;

  // wave tile: 2x2 waves of 32(M)x64(N), each 2x4 MFMA 16x16
  const int wm = (wid >> 1) * 32;
  const int wn = (wid & 1) * 64;
  const int fr = lane & 15;         // A/B fragment row: m (or n) = lane&15
  const int kg = (lane >> 4) * 8;   // k = (lane>>4)*8 + j

  f32x4 acc[2][4];
#pragma unroll
  for (int i = 0; i < 2; i++)
#pragma unroll
    for (int j = 0; j < 4; j++) acc[i][j] = (f32x4){0.f, 0.f, 0.f, 0.f};

  for (int k0 = 0; k0 < K_DIM; k0 += 32) {
    gll16(gA0, lA0);
    gll16(gB0, lB0); gll16(gB1, lB1);
    gA0 += 32; gB0 += 32; gB1 += 32;
    __syncthreads();  // barrier drains vmcnt -> LDS tiles ready

    bf16x8 af[2], bf[4];
#pragma unroll
    for (int mi = 0; mi < 2; mi++)
      af[mi] = *(const bf16x8*)(sA + (wm + mi * 16 + fr) * 32 + kg);
#pragma unroll
    for (int ni = 0; ni < 4; ni++)
      bf[ni] = *(const bf16x8*)(sB + (wn + ni * 16 + fr) * 32 + kg);

#pragma unroll
    for (int mi = 0; mi < 2; mi++)
#pragma unroll
      for (int ni = 0; ni < 4; ni++)
        acc[mi][ni] = __builtin_amdgcn_mfma_f32_16x16x32_bf16(
            af[mi], bf[ni], acc[mi][ni], 0, 0, 0);
    __syncthreads();  // protect LDS from next iteration's staging
  }

  // C/D layout: col = lane&15, row = (lane>>4)*4 + reg
  const int cr = (lane >> 4) * 4;
  const int cc = lane & 15;
#pragma unroll
  for (int mi = 0; mi < 2; mi++)
#pragma unroll
    for (int ni = 0; ni < 4; ni++) {
      float* cp = C + (size_t)(m0 + wm + mi * 16 + cr) * N_DIM +
                  (n0 + wn + ni * 16 + cc);
#pragma unroll
      for (int r = 0; r < 4; r++) cp[(size_t)r * N_DIM] = acc[mi][ni][r];
    }
}

extern "C" void kernel_launch(void* const* d_in, const int* in_sizes, int n_in,
                              void* d_out, int out_size, void* d_ws, size_t ws_size,
                              hipStream_t stream) {
  const float* x  = (const float*)d_in[0];   // (4,2048,1024,4) fp32
  const float* w  = (const float*)d_in[1];   // (1024,4) fp32
  const float* ws = (const float*)d_in[2];   // (1024,1024) fp32
  float* out = (float*)d_out;                // (4,2048,1024) fp32 = C[M][N]

  u16* xbf = (u16*)d_ws;                         // 33.5M u16 = 64 MB
  u16* w2  = xbf + (size_t)M_DIM * K_DIM;        // 4.2M u16 = 8 MB

  // 33,554,432 / (256*4) = 32768 blocks
  k_cvt<<<32768, 256, 0, stream>>>(x, xbf);
  // 1,048,576 / 256 = 4096 blocks
  k_w2<<<4096, 256, 0, stream>>>(w, ws, w2);

  dim3 grid(N_DIM / 128, M_DIM / 64);  // (8, 128) = 1024 blocks, 4/CU
  k_gemm<<<grid, 256, 0, stream>>>(xbf, w2, out);
}

// Round 4
// 302.135 us; speedup vs baseline: 1.1425x; 1.0379x over previous
//
#include <hip/hip_runtime.h>

typedef unsigned short u16;
typedef u16 u16x4 __attribute__((ext_vector_type(4)));
typedef float f32x4 __attribute__((ext_vector_type(4)));
typedef __bf16 bf16x8 __attribute__((ext_vector_type(8)));

#define M_DIM 8192   // B*H = 4*2048
#define N_DIM 1024   // O
#define K_DIM 4096   // I*(D+1) = 1024*4

__device__ __forceinline__ u16 f2bf(float f) {
  unsigned u = __float_as_uint(f);
  u += 0x7FFFu + ((u >> 16) & 1u);   // round-to-nearest-even
  return (u16)(u >> 16);
}

// ---- kernel 1: x fp32 -> bf16. 4 elems/thread: every instruction is
// lane-contiguous (16B/lane read, 8B/lane write). ----
__global__ __launch_bounds__(256) void k_cvt(const float* __restrict__ x,
                                             u16* __restrict__ y) {
  long i = ((long)blockIdx.x * 256 + threadIdx.x) * 4;
  f32x4 a = *(const f32x4*)(x + i);
  u16x4 r;
  r[0] = f2bf(a[0]); r[1] = f2bf(a[1]); r[2] = f2bf(a[2]); r[3] = f2bf(a[3]);
  *(u16x4*)(y + i) = r;
}

// ---- kernel 2: W2[o][i*4+d] = ws[o][i] * w[o][d], bf16 [N][K] ----
__global__ __launch_bounds__(256) void k_w2(const float* __restrict__ w,
                                            const float* __restrict__ ws,
                                            u16* __restrict__ w2) {
  int idx = blockIdx.x * 256 + threadIdx.x;  // idx = o*1024 + i
  int o = idx >> 10;
  float s = ws[idx];
  f32x4 wv = *(const f32x4*)(w + o * 4);
  u16x4 r;
  r[0] = f2bf(s * wv[0]); r[1] = f2bf(s * wv[1]);
  r[2] = f2bf(s * wv[2]); r[3] = f2bf(s * wv[3]);
  *(u16x4*)(w2 + (size_t)idx * 4) = r;
}

// ---- kernel 3: bf16 GEMM, 128x128 tile, 512 threads (8 waves).
// Grid (8,64)=512 blocks -> 2 blocks/CU x 8 waves = 16 waves/CU (50% occ),
// double R1's, with identical global traffic and best FLOP/staged-byte.
// Wave grid 4(M)x2(N), wave-tile 32x64 = 2x4 MFMA 16x16x32. ----
typedef __attribute__((address_space(1))) const void gvoid_t;
typedef __attribute__((address_space(3))) void lvoid_t;
__device__ __forceinline__ void gll16(const void* g, void* l) {
  __builtin_amdgcn_global_load_lds((gvoid_t*)g, (lvoid_t*)l, 16, 0, 0);
}

__global__ __launch_bounds__(512) void k_gemm(const u16* __restrict__ A,
                                              const u16* __restrict__ Bt,
                                              float* __restrict__ C) {
  __shared__ u16 sA[128 * 32];  // 8 KB, unpadded (global_load_lds lane-contig)
  __shared__ u16 sB[128 * 32];  // 8 KB

  const int t    = threadIdx.x;
  const int lane = t & 63;
  const int wid  = t >> 6;           // 0..7
  const int m0   = blockIdx.y * 128;
  const int n0   = blockIdx.x * 128;

  // staging: 512 chunks of 8 elems cover a 128x32 tile; chunk c = t:
  // row = t>>2, k-off = (t&3)*8. One chunk of A and one of B per thread.
  const int row0 = t >> 2;
  const int kc0  = (t & 3) * 8;
  const u16* gA0 = A  + (size_t)(m0 + row0) * K_DIM + kc0;
  const u16* gB0 = Bt + (size_t)(n0 + row0) * K_DIM + kc0;
  u16* lA0 = sA + t * 8;   // = wave base + lane*16B  (lane-contiguous) ✓
  u16* lB0 = sB + t * 8;

  // wave tile: 4(M)x2(N) waves of 32x64, each 2x4 MFMA 16x16
  const int wm = (wid >> 1) * 32;
  const int wn = (wid & 1) * 64;
  const int fr = lane & 15;         // A/B fragment row: m (or n) = lane&15
  const int kg = (lane >> 4) * 8;   // k = (lane>>4)*8 + j

  f32x4 acc[2][4];
#pragma unroll
  for (int i = 0; i < 2; i++)
#pragma unroll
    for (int j = 0; j < 4; j++) acc[i][j] = (f32x4){0.f, 0.f, 0.f, 0.f};

  for (int k0 = 0; k0 < K_DIM; k0 += 32) {
    gll16(gA0, lA0);
    gll16(gB0, lB0);
    gA0 += 32; gB0 += 32;
    __syncthreads();  // barrier drains vmcnt -> LDS tiles ready

    bf16x8 af[2], bf[4];
#pragma unroll
    for (int mi = 0; mi < 2; mi++)
      af[mi] = *(const bf16x8*)(sA + (wm + mi * 16 + fr) * 32 + kg);
#pragma unroll
    for (int ni = 0; ni < 4; ni++)
      bf[ni] = *(const bf16x8*)(sB + (wn + ni * 16 + fr) * 32 + kg);

#pragma unroll
    for (int mi = 0; mi < 2; mi++)
#pragma unroll
      for (int ni = 0; ni < 4; ni++)
        acc[mi][ni] = __builtin_amdgcn_mfma_f32_16x16x32_bf16(
            af[mi], bf[ni], acc[mi][ni], 0, 0, 0);
    __syncthreads();  // protect LDS from next iteration's staging
  }

  // C/D layout: col = lane&15, row = (lane>>4)*4 + reg
  const int cr = (lane >> 4) * 4;
  const int cc = lane & 15;
#pragma unroll
  for (int mi = 0; mi < 2; mi++)
#pragma unroll
    for (int ni = 0; ni < 4; ni++) {
      float* cp = C + (size_t)(m0 + wm + mi * 16 + cr) * N_DIM +
                  (n0 + wn + ni * 16 + cc);
#pragma unroll
      for (int r = 0; r < 4; r++) cp[(size_t)r * N_DIM] = acc[mi][ni][r];
    }
}

extern "C" void kernel_launch(void* const* d_in, const int* in_sizes, int n_in,
                              void* d_out, int out_size, void* d_ws, size_t ws_size,
                              hipStream_t stream) {
  const float* x  = (const float*)d_in[0];   // (4,2048,1024,4) fp32
  const float* w  = (const float*)d_in[1];   // (1024,4) fp32
  const float* ws = (const float*)d_in[2];   // (1024,1024) fp32
  float* out = (float*)d_out;                // (4,2048,1024) fp32 = C[M][N]

  u16* xbf = (u16*)d_ws;                         // 33.5M u16 = 64 MB
  u16* w2  = xbf + (size_t)M_DIM * K_DIM;        // 4.2M u16 = 8 MB

  // 33,554,432 / (256*4) = 32768 blocks
  k_cvt<<<32768, 256, 0, stream>>>(x, xbf);
  // 1,048,576 / 256 = 4096 blocks
  k_w2<<<4096, 256, 0, stream>>>(w, ws, w2);

  dim3 grid(N_DIM / 128, M_DIM / 128);  // (8, 64) = 512 blocks
  k_gemm<<<grid, 512, 0, stream>>>(xbf, w2, out);
}

// Round 5
// 279.481 us; speedup vs baseline: 1.2351x; 1.0811x over previous
//
#include <hip/hip_runtime.h>

typedef unsigned short u16;
typedef u16 u16x4 __attribute__((ext_vector_type(4)));
typedef float f32x4 __attribute__((ext_vector_type(4)));
typedef __bf16 bf16x8 __attribute__((ext_vector_type(8)));

#define M_DIM 8192   // B*H = 4*2048
#define N_DIM 1024   // O
#define K_DIM 4096   // I*(D+1) = 1024*4

__device__ __forceinline__ u16 f2bf(float f) {
  unsigned u = __float_as_uint(f);
  u += 0x7FFFu + ((u >> 16) & 1u);   // round-to-nearest-even
  return (u16)(u >> 16);
}

// ---- kernel 1: x fp32 -> bf16 (lane-contiguous 16B read / 8B write) ----
__global__ __launch_bounds__(256) void k_cvt(const float* __restrict__ x,
                                             u16* __restrict__ y) {
  long i = ((long)blockIdx.x * 256 + threadIdx.x) * 4;
  f32x4 a = *(const f32x4*)(x + i);
  u16x4 r;
  r[0] = f2bf(a[0]); r[1] = f2bf(a[1]); r[2] = f2bf(a[2]); r[3] = f2bf(a[3]);
  *(u16x4*)(y + i) = r;
}

// ---- kernel 2: W2[o][i*4+d] = ws[o][i] * w[o][d], bf16 [N][K] ----
__global__ __launch_bounds__(256) void k_w2(const float* __restrict__ w,
                                            const float* __restrict__ ws,
                                            u16* __restrict__ w2) {
  int idx = blockIdx.x * 256 + threadIdx.x;  // idx = o*1024 + i
  int o = idx >> 10;
  float s = ws[idx];
  f32x4 wv = *(const f32x4*)(w + o * 4);
  u16x4 r;
  r[0] = f2bf(s * wv[0]); r[1] = f2bf(s * wv[1]);
  r[2] = f2bf(s * wv[2]); r[3] = f2bf(s * wv[3]);
  *(u16x4*)(w2 + (size_t)idx * 4) = r;
}

// ---- kernel 3: bf16 GEMM, 128x128 tile, BK=64, 512 threads (8 waves),
// XOR-swizzled LDS (chunk cg of row r stored at cg^(r&7); 16B chunks).
// Frag reads hit all 8 bank groups (2-way = free) instead of 8-way.
// Swizzle lives in the per-lane GLOBAL address, so global_load_lds's
// lane-contiguous LDS dest (base + lane*16) is preserved. ----
typedef __attribute__((address_space(1))) const void gvoid_t;
typedef __attribute__((address_space(3))) void lvoid_t;
__device__ __forceinline__ void gll16(const void* g, void* l) {
  __builtin_amdgcn_global_load_lds((gvoid_t*)g, (lvoid_t*)l, 16, 0, 0);
}

__global__ __launch_bounds__(512) void k_gemm(const u16* __restrict__ A,
                                              const u16* __restrict__ Bt,
                                              float* __restrict__ C) {
  __shared__ u16 sA[128 * 64];  // 16 KB (swizzled)
  __shared__ u16 sB[128 * 64];  // 16 KB (swizzled)

  const int t    = threadIdx.x;
  const int lane = t & 63;
  const int wid  = t >> 6;           // 0..7
  const int m0   = blockIdx.y * 128;
  const int n0   = blockIdx.x * 128;

  // staging: 2048 chunks (A:1024 + B:1024), 4 gll16/thread.
  // LDS slot s holds global row r=s>>3, logical chunk cg=(s&7)^(r&7).
  const int s0 = t, s1 = t + 512;
  const int r0 = s0 >> 3, c0 = (s0 & 7) ^ (r0 & 7);
  const int r1 = s1 >> 3, c1 = (s1 & 7) ^ (r1 & 7);
  const u16* gA0 = A  + (size_t)(m0 + r0) * K_DIM + c0 * 8;
  const u16* gA1 = A  + (size_t)(m0 + r1) * K_DIM + c1 * 8;
  const u16* gB0 = Bt + (size_t)(n0 + r0) * K_DIM + c0 * 8;
  const u16* gB1 = Bt + (size_t)(n0 + r1) * K_DIM + c1 * 8;
  u16* lA0 = sA + s0 * 8;  u16* lA1 = sA + s1 * 8;
  u16* lB0 = sB + s0 * 8;  u16* lB1 = sB + s1 * 8;

  // wave tile: 4(M)x2(N) waves of 32x64, each 2x4 MFMA 16x16x32 per k-step
  const int wm = (wid >> 1) * 32;
  const int wn = (wid & 1) * 64;
  const int fr = lane & 15;         // fragment row
  const int lc = lane >> 4;         // logical chunk within 32-wide k-step

  f32x4 acc[2][4];
#pragma unroll
  for (int i = 0; i < 2; i++)
#pragma unroll
    for (int j = 0; j < 4; j++) acc[i][j] = (f32x4){0.f, 0.f, 0.f, 0.f};

  for (int k0 = 0; k0 < K_DIM; k0 += 64) {
    gll16(gA0, lA0); gll16(gA1, lA1);
    gll16(gB0, lB0); gll16(gB1, lB1);
    gA0 += 64; gA1 += 64; gB0 += 64; gB1 += 64;
    __syncthreads();  // tiles ready

#pragma unroll
    for (int ks = 0; ks < 2; ks++) {
      bf16x8 af[2], bf[4];
#pragma unroll
      for (int mi = 0; mi < 2; mi++) {
        int r  = wm + mi * 16 + fr;
        int pc = (ks * 4 + lc) ^ (r & 7);
        af[mi] = *(const bf16x8*)(sA + r * 64 + pc * 8);
      }
#pragma unroll
      for (int ni = 0; ni < 4; ni++) {
        int r  = wn + ni * 16 + fr;
        int pc = (ks * 4 + lc) ^ (r & 7);
        bf[ni] = *(const bf16x8*)(sB + r * 64 + pc * 8);
      }
#pragma unroll
      for (int mi = 0; mi < 2; mi++)
#pragma unroll
        for (int ni = 0; ni < 4; ni++)
          acc[mi][ni] = __builtin_amdgcn_mfma_f32_16x16x32_bf16(
              af[mi], bf[ni], acc[mi][ni], 0, 0, 0);
    }
    __syncthreads();  // protect LDS from next iteration's staging
  }

  // C/D layout: col = lane&15, row = (lane>>4)*4 + reg
  const int cr = (lane >> 4) * 4;
  const int cc = lane & 15;
#pragma unroll
  for (int mi = 0; mi < 2; mi++)
#pragma unroll
    for (int ni = 0; ni < 4; ni++) {
      float* cp = C + (size_t)(m0 + wm + mi * 16 + cr) * N_DIM +
                  (n0 + wn + ni * 16 + cc);
#pragma unroll
      for (int r = 0; r < 4; r++) cp[(size_t)r * N_DIM] = acc[mi][ni][r];
    }
}

extern "C" void kernel_launch(void* const* d_in, const int* in_sizes, int n_in,
                              void* d_out, int out_size, void* d_ws, size_t ws_size,
                              hipStream_t stream) {
  const float* x  = (const float*)d_in[0];   // (4,2048,1024,4) fp32
  const float* w  = (const float*)d_in[1];   // (1024,4) fp32
  const float* ws = (const float*)d_in[2];   // (1024,1024) fp32
  float* out = (float*)d_out;                // (4,2048,1024) fp32 = C[M][N]

  u16* xbf = (u16*)d_ws;                         // 33.5M u16 = 64 MB
  u16* w2  = xbf + (size_t)M_DIM * K_DIM;        // 4.2M u16 = 8 MB

  k_cvt<<<32768, 256, 0, stream>>>(x, xbf);
  k_w2<<<4096, 256, 0, stream>>>(w, ws, w2);

  dim3 grid(N_DIM / 128, M_DIM / 128);  // (8, 64) = 512 blocks, 2/CU
  k_gemm<<<grid, 512, 0, stream>>>(xbf, w2, out);
}